// Round 6
// baseline (256.386 us; speedup 1.0000x reference)
//
#include <hip/hip_runtime.h>
#include <math.h>

#define B_DIM 4096
#define K_DIM 4096
#define D_DIM 1024

typedef unsigned int uint32;
typedef __attribute__((ext_vector_type(4))) int i32x4;

// i8 screen: dot err rms ~0.06 -> act err rms ~3e-5, extremes ~1.2e-4.
#define W_ACT 4.0e-4f
// R4 measured ~100-150 raw emissions/row at W=4e-4; 768 = huge margin.
#define CAND_MAX 768

// quant scales (x ~ N(0,1): max|x| ~5.5 < 6; w ~ 0.1*N(0,1): max ~0.55 < 0.75)
#define QX (127.0f / 6.0f)
#define QW (127.0f / 0.75f)
#define DOT_SCALE ((6.0f * 0.75f) / (127.0f * 127.0f))

// ---------------- ws offsets (bytes) ----------------
#define N_XQ    0u
#define N_WQ    4194304u
#define N_S     8388608u
#define N_WN    (N_S + 0u)
#define N_RS    (N_S + 16384u)
#define N_XN    (N_S + 32768u)
#define N_RMX   (N_S + 49152u)
#define N_CNT   (N_S + 65536u)
#define N_WIN   (N_S + 81920u)
#define N_LP    (N_S + 98304u)
#define N_IDX   (N_S + 114688u)
#define N_CK    (N_S + 131072u)            // 4096*768*4 = 12582912
#define N_CA    (N_S + 12713984u)          // 12582912; end ~32.1 MB (< 34.18 proven)

// ---------------- helpers ----------------
typedef const __attribute__((address_space(1))) void gvoid_t;
typedef __attribute__((address_space(3))) void svoid_t;
__device__ __forceinline__ void async_copy16(const char* g, const char* l) {
  __builtin_amdgcn_global_load_lds((gvoid_t*)g, (svoid_t*)l, 16, 0, 0);
}

__device__ __forceinline__ int q8(float v, float s) {
  int q = (int)rintf(v * s);
  q = q > 127 ? 127 : q;
  q = q < -127 ? -127 : q;
  return q & 0xff;
}
__device__ __forceinline__ uint32 pack4(float4 v, float s) {
  return (uint32)q8(v.x, s) | ((uint32)q8(v.y, s) << 8) |
         ((uint32)q8(v.z, s) << 16) | ((uint32)q8(v.w, s) << 24);
}

// ---- reference-exact activation ----
__device__ __forceinline__ float act_of(float xn, float wn, float dot,
                                        float rs, float rsd) {
  float dist = (xn + wn) - 2.0f * dot;
  float dw   = dist * rsd;
  return rs / ((rs + dw) + 1e-7f);
}

// ---------------- prep: norms, rel_sum, i8 quant of x and w, inits ----------------
__global__ __launch_bounds__(256) void prep_quant_kernel(
    const float* __restrict__ x, const float* __restrict__ w,
    const float* __restrict__ rel,
    char* __restrict__ xq, char* __restrict__ wq,
    float* __restrict__ w_norm, float* __restrict__ rel_sum,
    float* __restrict__ x_norm,
    float* __restrict__ rowmax_g, int* __restrict__ cnt,
    int* __restrict__ winner) {
  int row  = blockIdx.x * 4 + (threadIdx.x >> 6);
  int lane = threadIdx.x & 63;
  if (row < K_DIM) {
    const float4* wr = (const float4*)(w   + (size_t)row * D_DIM);
    const float4* rr = (const float4*)(rel + (size_t)row * D_DIM);
    uint32* qp = (uint32*)(wq + (size_t)row * D_DIM);
    float s2 = 0.f, sr = 0.f;
#pragma unroll
    for (int q = 0; q < 4; ++q) {
      float4 wv = wr[lane + 64 * q];
      float4 rv = rr[lane + 64 * q];
      s2 += wv.x * wv.x + wv.y * wv.y + wv.z * wv.z + wv.w * wv.w;
      sr += rv.x + rv.y + rv.z + rv.w;
      qp[lane + 64 * q] = pack4(wv, QW);
    }
    for (int m = 1; m < 64; m <<= 1) {
      s2 += __shfl_xor(s2, m, 64);
      sr += __shfl_xor(sr, m, 64);
    }
    if (lane == 0) { w_norm[row] = s2; rel_sum[row] = sr; winner[row] = -1; }
  } else {
    int rb = row - K_DIM;
    const float4* xr = (const float4*)(x + (size_t)rb * D_DIM);
    uint32* qp = (uint32*)(xq + (size_t)rb * D_DIM);
    float s2 = 0.f;
#pragma unroll
    for (int q = 0; q < 4; ++q) {
      float4 xv = xr[lane + 64 * q];
      s2 += xv.x * xv.x + xv.y * xv.y + xv.z * xv.z + xv.w * xv.w;
      qp[lane + 64 * q] = pack4(xv, QX);
    }
    for (int m = 1; m < 64; m <<= 1) s2 += __shfl_xor(s2, m, 64);
    if (lane == 0) { x_norm[rb] = s2; cnt[rb] = 0; rowmax_g[rb] = 0.f; }
  }
}

// ---------------- Pass A: i8 GEMM (K=64 MFMA) -> candidate shortlist + row maxima ----
// grid (B/128, K/128), block 256 (4 waves, 2x2 of 64x64). BK=64 -> 16 iters.
__global__ __launch_bounds__(256) void mfma_screen_kernel(
    const char* __restrict__ xq, const char* __restrict__ wq,
    const float* __restrict__ w_norm, const float* __restrict__ rel_sum,
    const float* __restrict__ x_norm,
    float* __restrict__ rowmax_g, int* __restrict__ cnt,
    int* __restrict__ cand_k, float* __restrict__ cand_a) {
  __shared__ __align__(16) char lds[16384];   // Ah|Bh, each 128x64 i8
  char* Ah = lds;
  char* Bh = lds + 8192;

  const int tid    = threadIdx.x;
  const int wid    = tid >> 6;
  const int lane   = tid & 63;
  const int quad   = lane >> 4;
  const int l15    = lane & 15;
  const int wave_r = wid >> 1;
  const int wave_c = wid & 1;
  const int row0   = blockIdx.x * 128;
  const int col0   = blockIdx.y * 128;

  // staging lane geometry (identical 16-row x 4x16B-granule tile as proven bf16)
  const int srow = lane >> 2;
  const int skq  = (lane & 3) ^ ((lane >> 3) & 3);
  const int fswz = quad ^ ((l15 >> 1) & 3);

  i32x4 acc[4][4];
#pragma unroll
  for (int i = 0; i < 4; ++i)
#pragma unroll
    for (int j = 0; j < 4; ++j)
#pragma unroll
      for (int r = 0; r < 4; ++r) acc[i][j][r] = 0;

  for (int k0 = 0; k0 < D_DIM; k0 += 64) {
    __syncthreads();
#pragma unroll
    for (int t = 0; t < 2; ++t) {
      const int c = wid * 2 + t;           // 16-row chunk, 1 KB per array
      const size_t ga = (size_t)(row0 + c * 16 + srow) * D_DIM + k0 + skq * 16;
      const size_t gb = (size_t)(col0 + c * 16 + srow) * D_DIM + k0 + skq * 16;
      async_copy16(xq + ga, Ah + c * 1024);
      async_copy16(wq + gb, Bh + c * 1024);
    }
    __syncthreads();

    i32x4 af[4], bf[4];
#pragma unroll
    for (int f = 0; f < 4; ++f) {
      af[f] = *(const i32x4*)(Ah + (wave_r * 64 + f * 16 + l15) * 64 + fswz * 16);
      bf[f] = *(const i32x4*)(Bh + (wave_c * 64 + f * 16 + l15) * 64 + fswz * 16);
    }
#pragma unroll
    for (int i = 0; i < 4; ++i)
#pragma unroll
      for (int j = 0; j < 4; ++j)
        acc[i][j] = __builtin_amdgcn_mfma_i32_16x16x64_i8(af[i], bf[j], acc[i][j], 0, 0, 0);
  }

  // ---- epilogue: act (stored as float bits in acc), block row-max, emission ----
  float xnv[4][4];
#pragma unroll
  for (int fi = 0; fi < 4; ++fi)
#pragma unroll
    for (int r = 0; r < 4; ++r)
      xnv[fi][r] = x_norm[row0 + wave_r * 64 + fi * 16 + quad * 4 + r];

  float bestA[4][4];
#pragma unroll
  for (int fi = 0; fi < 4; ++fi)
#pragma unroll
    for (int r = 0; r < 4; ++r) bestA[fi][r] = -INFINITY;

#pragma unroll
  for (int fj = 0; fj < 4; ++fj) {
    const int k = col0 + wave_c * 64 + fj * 16 + l15;
    const float rs  = rel_sum[k];
    const float wn  = w_norm[k];
    const float rsd = rs * (1.0f / 1024.0f);
#pragma unroll
    for (int fi = 0; fi < 4; ++fi)
#pragma unroll
      for (int r = 0; r < 4; ++r) {
        float dot = (float)acc[fi][fj][r] * DOT_SCALE;
        float act = act_of(xnv[fi][r], wn, dot, rs, rsd);
        acc[fi][fj][r] = __float_as_int(act);
        bestA[fi][r] = fmaxf(bestA[fi][r], act);
      }
  }

#pragma unroll
  for (int m = 1; m < 16; m <<= 1)
#pragma unroll
    for (int fi = 0; fi < 4; ++fi)
#pragma unroll
      for (int r = 0; r < 4; ++r)
        bestA[fi][r] = fmaxf(bestA[fi][r], __shfl_xor(bestA[fi][r], m, 64));

  __syncthreads();   // tile LDS no longer needed
  float* sA   = (float*)lds;          // [2][128]
  float* sMax = (float*)lds + 256;    // [128]
  if (l15 == 0) {
#pragma unroll
    for (int fi = 0; fi < 4; ++fi)
#pragma unroll
      for (int r = 0; r < 4; ++r)
        sA[wave_c * 128 + wave_r * 64 + fi * 16 + quad * 4 + r] = bestA[fi][r];
  }
  __syncthreads();
  if (tid < 128) {
    float m = fmaxf(sA[tid], sA[128 + tid]);
    sMax[tid] = m;
    atomicMax((int*)rowmax_g + (row0 + tid), __float_as_int(m));  // acts > 0
  }
  __syncthreads();

#pragma unroll
  for (int fi = 0; fi < 4; ++fi)
#pragma unroll
    for (int r = 0; r < 4; ++r) {
      const int row_local = wave_r * 64 + fi * 16 + quad * 4 + r;
      const float thr = sMax[row_local] - W_ACT;
      const int grow = row0 + row_local;
#pragma unroll
      for (int fj = 0; fj < 4; ++fj) {
        float a = __int_as_float(acc[fi][fj][r]);
        if (a >= thr) {
          int k = col0 + wave_c * 64 + fj * 16 + l15;
          int p = atomicAdd(&cnt[grow], 1);
          if (p < CAND_MAX) {
            cand_k[(size_t)grow * CAND_MAX + p] = k;
            cand_a[(size_t)grow * CAND_MAX + p] = a;
          }
        }
      }
    }
}

// ---------------- Pass B: filter + exact refine + winner + loss partial ----------------
__global__ __launch_bounds__(256) void scan_refine_kernel(
    const int* __restrict__ cand_k, const float* __restrict__ cand_a,
    const int* __restrict__ cnt, const float* __restrict__ rowmax_g,
    const float* __restrict__ x, const float* __restrict__ w,
    const float* __restrict__ w_norm, const float* __restrict__ rel_sum,
    const float* __restrict__ x_norm,
    int* __restrict__ idx_int, float* __restrict__ out_idx,
    int* __restrict__ winner, float* __restrict__ lparts) {
  const int b = blockIdx.x;
  const int t = threadIdx.x;
  const int wv = t >> 6, ln = t & 63;

  __shared__ int   sk[CAND_MAX];
  __shared__ float sdot[CAND_MAX];
  __shared__ int   scnt;
  __shared__ int   sBI;
  __shared__ float swA[4];
  __shared__ int   swI[4];
  __shared__ float sl[4];

  const float4* xr = (const float4*)(x + (size_t)b * D_DIM);
  float4 xv[4];
#pragma unroll
  for (int q = 0; q < 4; ++q) xv[q] = xr[ln + 64 * q];

  const int n_raw = cnt[b];
  const float thr = rowmax_g[b] - W_ACT;
  const float xn = x_norm[b];
  if (t == 0) scnt = 0;
  __syncthreads();

  if (n_raw <= CAND_MAX) {
    for (int i = t; i < n_raw; i += 256) {
      if (cand_a[(size_t)b * CAND_MAX + i] >= thr) {
        int p = atomicAdd(&scnt, 1);
        sk[p] = cand_k[(size_t)b * CAND_MAX + i];
      }
    }
    __syncthreads();
    const int n = scnt;
    for (int c = wv; c < n; c += 4) {
      int k = sk[c];
      const float4* wr = (const float4*)(w + (size_t)k * D_DIM);
      float s = 0.f;
#pragma unroll
      for (int q = 0; q < 4; ++q) {
        float4 wv4 = wr[ln + 64 * q];
        s += xv[q].x * wv4.x + xv[q].y * wv4.y + xv[q].z * wv4.z + xv[q].w * wv4.w;
      }
      for (int m = 1; m < 64; m <<= 1) s += __shfl_xor(s, m, 64);
      if (ln == 0) sdot[c] = s;
    }
    __syncthreads();
    if (t == 0) {
      float bA = -INFINITY; int bI = 0x7fffffff;
      for (int c = 0; c < n; ++c) {
        int k = sk[c];
        float rs = rel_sum[k];
        float act = act_of(xn, w_norm[k], sdot[c], rs, rs * (1.0f / 1024.0f));
        if (act > bA || (act == bA && k < bI)) { bA = act; bI = k; }
      }
      idx_int[b] = bI;
      out_idx[b] = (float)bI;
      atomicMax(&winner[bI], b);
      sBI = bI;
    }
  } else {
    // safety valve (statistically unreachable at CAND_MAX=768)
    float bA = -INFINITY; int bI = 0x7fffffff;
    for (int k = wv; k < K_DIM; k += 4) {
      const float4* wr = (const float4*)(w + (size_t)k * D_DIM);
      float s = 0.f;
#pragma unroll
      for (int q = 0; q < 4; ++q) {
        float4 wv4 = wr[ln + 64 * q];
        s += xv[q].x * wv4.x + xv[q].y * wv4.y + xv[q].z * wv4.z + xv[q].w * wv4.w;
      }
      for (int m = 1; m < 64; m <<= 1) s += __shfl_xor(s, m, 64);
      if (ln == 0) {
        float rs = rel_sum[k];
        float act = act_of(xn, w_norm[k], s, rs, rs * (1.0f / 1024.0f));
        if (act > bA || (act == bA && k < bI)) { bA = act; bI = k; }
      }
    }
    if (ln == 0) { swA[wv] = bA; swI[wv] = bI; }
    __syncthreads();
    if (t == 0) {
      float bA2 = -INFINITY; int bI2 = 0x7fffffff;
#pragma unroll
      for (int c = 0; c < 4; ++c) {
        if (swA[c] > bA2 || (swA[c] == bA2 && swI[c] < bI2)) { bA2 = swA[c]; bI2 = swI[c]; }
      }
      idx_int[b] = bI2;
      out_idx[b] = (float)bI2;
      atomicMax(&winner[bI2], b);
      sBI = bI2;
    }
  }
  __syncthreads();

  const int bI = sBI;
  float4 xt = xr[t];
  float4 wt = ((const float4*)(w + (size_t)bI * D_DIM))[t];
  float s = (xt.x - wt.x) + (xt.y - wt.y) + (xt.z - wt.z) + (xt.w - wt.w);
  for (int m = 1; m < 64; m <<= 1) s += __shfl_xor(s, m, 64);
  if (ln == 0) sl[wv] = s;
  __syncthreads();
  if (t == 0) lparts[b] = sl[0] + sl[1] + sl[2] + sl[3];
}

// ---------------- scatter update / pass-through (+ fused loss reduction) ----------------
__global__ __launch_bounds__(256) void update_kernel(
    const float* __restrict__ x, const float* __restrict__ w,
    const float* __restrict__ ma, const float* __restrict__ rel,
    const int* __restrict__ winner, const float* __restrict__ lparts,
    float* __restrict__ out_w, float* __restrict__ out_ma,
    float* __restrict__ out_rel, float* __restrict__ out_loss) {
  const int k = blockIdx.x;
  const int t = threadIdx.x;

  if (k == K_DIM) {   // fused loss_final
    double acc = 0.0;
    for (int i = t; i < B_DIM; i += 256) acc += (double)lparts[i];
    for (int m = 1; m < 64; m <<= 1) acc += __shfl_xor(acc, m, 64);
    __shared__ double sa[4];
    if ((t & 63) == 0) sa[t >> 6] = acc;
    __syncthreads();
    if (t == 0)
      out_loss[0] = (float)(0.3 * (sa[0] + sa[1] + sa[2] + sa[3]) / (double)B_DIM);
    return;
  }

  const size_t ro = (size_t)k * D_DIM;
  const int bw = winner[k];
  if (bw < 0) {
    float4 a = ((const float4*)(w   + ro))[t];
    float4 b = ((const float4*)(ma  + ro))[t];
    float4 c = ((const float4*)(rel + ro))[t];
    ((float4*)(out_w   + ro))[t] = a;
    ((float4*)(out_ma  + ro))[t] = b;
    ((float4*)(out_rel + ro))[t] = c;
    return;
  }
  const float a_c = (float)(0.3 * 1e-4);
  const float omc = (float)(1.0 - 0.3 * 1e-4);
  float4 xv  = ((const float4*)(x  + (size_t)bw * D_DIM))[t];
  float4 wv4 = ((const float4*)(w  + ro))[t];
  float4 mav = ((const float4*)(ma + ro))[t];
  float4 nm;
  nm.x = a_c * fabsf(xv.x - wv4.x) + omc * mav.x;
  nm.y = a_c * fabsf(xv.y - wv4.y) + omc * mav.y;
  nm.z = a_c * fabsf(xv.z - wv4.z) + omc * mav.z;
  nm.w = a_c * fabsf(xv.w - wv4.w) + omc * mav.w;

  float tmx = fmaxf(fmaxf(nm.x, nm.y), fmaxf(nm.z, nm.w));
  float tmn = fminf(fminf(nm.x, nm.y), fminf(nm.z, nm.w));
  float tsm = nm.x + nm.y + nm.z + nm.w;
  for (int m = 1; m < 64; m <<= 1) {
    tmx = fmaxf(tmx, __shfl_xor(tmx, m, 64));
    tmn = fminf(tmn, __shfl_xor(tmn, m, 64));
    tsm += __shfl_xor(tsm, m, 64);
  }
  __shared__ float smx[4], smn[4], ssm[4];
  if ((t & 63) == 0) { smx[t >> 6] = tmx; smn[t >> 6] = tmn; ssm[t >> 6] = tsm; }
  __syncthreads();
  if (t == 0) {
    float m1 = fmaxf(fmaxf(smx[0], smx[1]), fmaxf(smx[2], smx[3]));
    float m2 = fminf(fminf(smn[0], smn[1]), fminf(smn[2], smn[3]));
    float s1 = ssm[0] + ssm[1] + ssm[2] + ssm[3];
    smx[0] = m1; smn[0] = m2; ssm[0] = s1;
  }
  __syncthreads();
  const float mx  = smx[0];
  const float mn  = smn[0];
  const float avg = ssm[0] * (1.0f / 1024.0f);
  const float den = 0.01f * (mx - mn);

  float4 rl;
  rl.x = 1.0f / (1.0f + expf((nm.x - avg) / den));
  rl.y = 1.0f / (1.0f + expf((nm.y - avg) / den));
  rl.z = 1.0f / (1.0f + expf((nm.z - avg) / den));
  rl.w = 1.0f / (1.0f + expf((nm.w - avg) / den));
  if (isnan(rl.x)) rl.x = 1.0f;
  if (isnan(rl.y)) rl.y = 1.0f;
  if (isnan(rl.z)) rl.z = 1.0f;
  if (isnan(rl.w)) rl.w = 1.0f;

  float4 nw;
  nw.x = wv4.x + 0.3f * (xv.x - wv4.x);
  nw.y = wv4.y + 0.3f * (xv.y - wv4.y);
  nw.z = wv4.z + 0.3f * (xv.z - wv4.z);
  nw.w = wv4.w + 0.3f * (xv.w - wv4.w);

  ((float4*)(out_w   + ro))[t] = nw;
  ((float4*)(out_ma  + ro))[t] = nm;
  ((float4*)(out_rel + ro))[t] = rl;
}

extern "C" void kernel_launch(void* const* d_in, const int* in_sizes, int n_in,
                              void* d_out, int out_size, void* d_ws, size_t ws_size,
                              hipStream_t stream) {
  const float* x   = (const float*)d_in[0];
  const float* w   = (const float*)d_in[1];
  const float* ma  = (const float*)d_in[2];
  const float* rel = (const float*)d_in[3];

  float* out      = (float*)d_out;
  float* out_loss = out;
  float* out_idx  = out + 1;
  float* out_w    = out + 1 + B_DIM;
  float* out_ma   = out_w  + (size_t)K_DIM * D_DIM;
  float* out_rel  = out_ma + (size_t)K_DIM * D_DIM;

  char* ws = (char*)d_ws;
  char*  xq       = (char*)(ws + N_XQ);
  char*  wq       = (char*)(ws + N_WQ);
  float*  w_norm   = (float*)(ws + N_WN);
  float*  rel_sum  = (float*)(ws + N_RS);
  float*  x_norm   = (float*)(ws + N_XN);
  float*  rowmax_g = (float*)(ws + N_RMX);
  int*    cnt      = (int*)  (ws + N_CNT);
  int*    winner   = (int*)  (ws + N_WIN);
  float*  lparts   = (float*)(ws + N_LP);
  int*    idx_int  = (int*)  (ws + N_IDX);
  int*    cand_k   = (int*)  (ws + N_CK);
  float*  cand_a   = (float*)(ws + N_CA);

  prep_quant_kernel<<<(K_DIM + B_DIM) / 4, 256, 0, stream>>>(
      x, w, rel, xq, wq, w_norm, rel_sum, x_norm, rowmax_g, cnt, winner);
  mfma_screen_kernel<<<dim3(B_DIM / 128, K_DIM / 128), 256, 0, stream>>>(
      xq, wq, w_norm, rel_sum, x_norm, rowmax_g, cnt, cand_k, cand_a);
  scan_refine_kernel<<<B_DIM, 256, 0, stream>>>(
      cand_k, cand_a, cnt, rowmax_g, x, w, w_norm, rel_sum, x_norm,
      idx_int, out_idx, winner, lparts);
  update_kernel<<<K_DIM + 1, 256, 0, stream>>>(
      x, w, ma, rel, winner, lparts, out_w, out_ma, out_rel, out_loss);
}

// Round 7
// 221.031 us; speedup vs baseline: 1.1600x; 1.1600x over previous
//
#include <hip/hip_runtime.h>
#include <math.h>

#define B_DIM 4096
#define K_DIM 4096
#define D_DIM 1024

typedef unsigned int uint32;
typedef __attribute__((ext_vector_type(8))) short short8;
typedef __attribute__((ext_vector_type(4))) float f32x4;

// Screen act-error std ~2.4e-6; extreme (5.5 sigma over 16.7M) ~1.3e-5.
// Emission/capture window (needs >= 2*eps_extreme ~ 2.6e-5): 1e-4 (4x margin).
#define W_ACT 1.0e-4f
// Refine filter (same correctness bound, 1.9x margin; ~12-15 exact dots/row):
#define W_REFINE 5.0e-5f
#define CAND_MAX 384

// ---------------- ws offsets (bytes) ----------------
#define N_XH    0u
#define N_WH    8388608u
#define N_S     16777216u
#define N_WN    (N_S + 0u)
#define N_RS    (N_S + 16384u)
#define N_XN    (N_S + 32768u)
#define N_RMX   (N_S + 49152u)
#define N_CNT   (N_S + 65536u)
#define N_WIN   (N_S + 81920u)
#define N_LP    (N_S + 98304u)
#define N_IDX   (N_S + 114688u)
#define N_CK    (N_S + 131072u)            // 4096*384*4 = 6291456
#define N_CA    (N_S + 6422528u)           // 6291456; end ~29.5 MB

// ---------------- helpers ----------------
__device__ __forceinline__ unsigned short f2bf(float f) {
  uint32 u = __float_as_uint(f);
  uint32 r = (u + 0x7fffu + ((u >> 16) & 1u)) >> 16;
  return (unsigned short)r;
}

typedef const __attribute__((address_space(1))) void gvoid_t;
typedef __attribute__((address_space(3))) void svoid_t;
__device__ __forceinline__ void async_copy16(const unsigned short* g, const short* l) {
  __builtin_amdgcn_global_load_lds((gvoid_t*)g, (svoid_t*)l, 16, 0, 0);
}

// ---- reference-exact activation ----
__device__ __forceinline__ float act_of(float xn, float wn, float dot,
                                        float rs, float rsd) {
  float dist = (xn + wn) - 2.0f * dot;
  float dw   = dist * rsd;
  return rs / ((rs + dw) + 1e-7f);
}

// ---------------- prep+convert: norms, rel_sum, bf16-hi, inits ----------------
__global__ __launch_bounds__(256) void prep_convert_kernel(
    const float* __restrict__ x, const float* __restrict__ w,
    const float* __restrict__ rel,
    unsigned short* __restrict__ xh, unsigned short* __restrict__ wh,
    float* __restrict__ w_norm, float* __restrict__ rel_sum,
    float* __restrict__ x_norm,
    float* __restrict__ rowmax_g, int* __restrict__ cnt,
    int* __restrict__ winner) {
  int row  = blockIdx.x * 4 + (threadIdx.x >> 6);
  int lane = threadIdx.x & 63;
  if (row < K_DIM) {
    const float4* wr = (const float4*)(w   + (size_t)row * D_DIM);
    const float4* rr = (const float4*)(rel + (size_t)row * D_DIM);
    ushort4* hp = (ushort4*)(wh + (size_t)row * D_DIM);
    float s2 = 0.f, sr = 0.f;
#pragma unroll
    for (int q = 0; q < 4; ++q) {
      float4 wv = wr[lane + 64 * q];
      float4 rv = rr[lane + 64 * q];
      s2 += wv.x * wv.x + wv.y * wv.y + wv.z * wv.z + wv.w * wv.w;
      sr += rv.x + rv.y + rv.z + rv.w;
      ushort4 hv;
      hv.x = f2bf(wv.x); hv.y = f2bf(wv.y); hv.z = f2bf(wv.z); hv.w = f2bf(wv.w);
      hp[lane + 64 * q] = hv;
    }
    for (int m = 1; m < 64; m <<= 1) {
      s2 += __shfl_xor(s2, m, 64);
      sr += __shfl_xor(sr, m, 64);
    }
    if (lane == 0) { w_norm[row] = s2; rel_sum[row] = sr; winner[row] = -1; }
  } else {
    int rb = row - K_DIM;
    const float4* xr = (const float4*)(x + (size_t)rb * D_DIM);
    ushort4* hp = (ushort4*)(xh + (size_t)rb * D_DIM);
    float s2 = 0.f;
#pragma unroll
    for (int q = 0; q < 4; ++q) {
      float4 xv = xr[lane + 64 * q];
      s2 += xv.x * xv.x + xv.y * xv.y + xv.z * xv.z + xv.w * xv.w;
      ushort4 hv;
      hv.x = f2bf(xv.x); hv.y = f2bf(xv.y); hv.z = f2bf(xv.z); hv.w = f2bf(xv.w);
      hp[lane + 64 * q] = hv;
    }
    for (int m = 1; m < 64; m <<= 1) s2 += __shfl_xor(s2, m, 64);
    if (lane == 0) { x_norm[rb] = s2; cnt[rb] = 0; rowmax_g[rb] = 0.f; }
  }
}

// ---------------- Pass A: bf16 GEMM -> candidate shortlist + row maxima ----------------
// (exact R5 structure: VGPR 96, 91 us proven)
__global__ __launch_bounds__(256) void mfma_screen_kernel(
    const unsigned short* __restrict__ xh, const unsigned short* __restrict__ wh,
    const float* __restrict__ w_norm, const float* __restrict__ rel_sum,
    const float* __restrict__ x_norm,
    float* __restrict__ rowmax_g, int* __restrict__ cnt,
    int* __restrict__ cand_k, float* __restrict__ cand_a) {
  __shared__ __align__(16) short lds[8192];   // Ah|Bh, each 128x32 bf16
  short* Ah = lds;
  short* Bh = lds + 4096;

  const int tid    = threadIdx.x;
  const int wid    = tid >> 6;
  const int lane   = tid & 63;
  const int quad   = lane >> 4;
  const int l15    = lane & 15;
  const int wave_r = wid >> 1;
  const int wave_c = wid & 1;
  const int row0   = blockIdx.x * 128;
  const int col0   = blockIdx.y * 128;

  const int srow = lane >> 2;
  const int skq  = (lane & 3) ^ ((lane >> 3) & 3);
  const int fswz = quad ^ ((l15 >> 1) & 3);

  f32x4 acc[4][4];
#pragma unroll
  for (int i = 0; i < 4; ++i)
#pragma unroll
    for (int j = 0; j < 4; ++j)
#pragma unroll
      for (int r = 0; r < 4; ++r) acc[i][j][r] = 0.f;

  for (int k0 = 0; k0 < D_DIM; k0 += 32) {
    __syncthreads();
#pragma unroll
    for (int t = 0; t < 2; ++t) {
      const int c = wid * 2 + t;
      const size_t ga = (size_t)(row0 + c * 16 + srow) * D_DIM + k0 + skq * 8;
      const size_t gb = (size_t)(col0 + c * 16 + srow) * D_DIM + k0 + skq * 8;
      async_copy16(xh + ga, Ah + c * 512);
      async_copy16(wh + gb, Bh + c * 512);
    }
    __syncthreads();

    short8 af[4], bf[4];
#pragma unroll
    for (int f = 0; f < 4; ++f) {
      af[f] = *(const short8*)(Ah + (wave_r * 64 + f * 16 + l15) * 32 + fswz * 8);
      bf[f] = *(const short8*)(Bh + (wave_c * 64 + f * 16 + l15) * 32 + fswz * 8);
    }
#pragma unroll
    for (int i = 0; i < 4; ++i)
#pragma unroll
      for (int j = 0; j < 4; ++j)
        acc[i][j] = __builtin_amdgcn_mfma_f32_16x16x32_bf16(af[i], bf[j], acc[i][j], 0, 0, 0);
  }

  // ---- epilogue: act (overwrites acc), block row-max, candidate emission ----
  float xnv[4][4];
#pragma unroll
  for (int fi = 0; fi < 4; ++fi)
#pragma unroll
    for (int r = 0; r < 4; ++r)
      xnv[fi][r] = x_norm[row0 + wave_r * 64 + fi * 16 + quad * 4 + r];

  float bestA[4][4];
#pragma unroll
  for (int fi = 0; fi < 4; ++fi)
#pragma unroll
    for (int r = 0; r < 4; ++r) bestA[fi][r] = -INFINITY;

#pragma unroll
  for (int fj = 0; fj < 4; ++fj) {
    const int k = col0 + wave_c * 64 + fj * 16 + l15;
    const float rs  = rel_sum[k];
    const float wn  = w_norm[k];
    const float rsd = rs * (1.0f / 1024.0f);
#pragma unroll
    for (int fi = 0; fi < 4; ++fi)
#pragma unroll
      for (int r = 0; r < 4; ++r) {
        float act = act_of(xnv[fi][r], wn, acc[fi][fj][r], rs, rsd);
        acc[fi][fj][r] = act;
        bestA[fi][r] = fmaxf(bestA[fi][r], act);
      }
  }

#pragma unroll
  for (int m = 1; m < 16; m <<= 1)
#pragma unroll
    for (int fi = 0; fi < 4; ++fi)
#pragma unroll
      for (int r = 0; r < 4; ++r)
        bestA[fi][r] = fmaxf(bestA[fi][r], __shfl_xor(bestA[fi][r], m, 64));

  __syncthreads();
  float* sA   = (float*)lds;          // [2][128]
  float* sMax = (float*)lds + 256;    // [128]
  if (l15 == 0) {
#pragma unroll
    for (int fi = 0; fi < 4; ++fi)
#pragma unroll
      for (int r = 0; r < 4; ++r)
        sA[wave_c * 128 + wave_r * 64 + fi * 16 + quad * 4 + r] = bestA[fi][r];
  }
  __syncthreads();
  if (tid < 128) {
    float m = fmaxf(sA[tid], sA[128 + tid]);
    sMax[tid] = m;
    atomicMax((int*)rowmax_g + (row0 + tid), __float_as_int(m));  // acts > 0
  }
  __syncthreads();

#pragma unroll
  for (int fi = 0; fi < 4; ++fi)
#pragma unroll
    for (int r = 0; r < 4; ++r) {
      const int row_local = wave_r * 64 + fi * 16 + quad * 4 + r;
      const float thr = sMax[row_local] - W_ACT;
      const int grow = row0 + row_local;
#pragma unroll
      for (int fj = 0; fj < 4; ++fj) {
        float a = acc[fi][fj][r];
        if (a >= thr) {
          int k = col0 + wave_c * 64 + fj * 16 + l15;
          int p = atomicAdd(&cnt[grow], 1);
          if (p < CAND_MAX) {
            cand_k[(size_t)grow * CAND_MAX + p] = k;
            cand_a[(size_t)grow * CAND_MAX + p] = a;
          }
        }
      }
    }
}

// ---------------- Pass B: filter (5e-5) + exact refine + parallel select ----------------
__global__ __launch_bounds__(256) void scan_refine_kernel(
    const int* __restrict__ cand_k, const float* __restrict__ cand_a,
    const int* __restrict__ cnt, const float* __restrict__ rowmax_g,
    const float* __restrict__ x, const float* __restrict__ w,
    const float* __restrict__ w_norm, const float* __restrict__ rel_sum,
    const float* __restrict__ x_norm,
    int* __restrict__ idx_int, float* __restrict__ out_idx,
    int* __restrict__ winner, float* __restrict__ lparts) {
  const int b = blockIdx.x;
  const int t = threadIdx.x;
  const int wv = t >> 6, ln = t & 63;

  __shared__ int   sk[CAND_MAX];
  __shared__ float sdot[CAND_MAX];
  __shared__ int   scnt;
  __shared__ int   sBI;
  __shared__ float swA[4];
  __shared__ int   swI[4];
  __shared__ float sl[4];

  const float4* xr = (const float4*)(x + (size_t)b * D_DIM);
  float4 xv[4];
#pragma unroll
  for (int q = 0; q < 4; ++q) xv[q] = xr[ln + 64 * q];

  const int n_raw = cnt[b];
  const float thr = rowmax_g[b] - W_REFINE;
  const float xn = x_norm[b];
  if (t == 0) scnt = 0;
  __syncthreads();

  if (n_raw <= CAND_MAX) {
    for (int i = t; i < n_raw; i += 256) {
      if (cand_a[(size_t)b * CAND_MAX + i] >= thr) {
        int p = atomicAdd(&scnt, 1);
        sk[p] = cand_k[(size_t)b * CAND_MAX + i];
      }
    }
    __syncthreads();
    const int n = scnt;
    // exact fp32 dots, one wave per candidate
    for (int c = wv; c < n; c += 4) {
      int k = sk[c];
      const float4* wr = (const float4*)(w + (size_t)k * D_DIM);
      float s = 0.f;
#pragma unroll
      for (int q = 0; q < 4; ++q) {
        float4 wv4 = wr[ln + 64 * q];
        s += xv[q].x * wv4.x + xv[q].y * wv4.y + xv[q].z * wv4.z + xv[q].w * wv4.w;
      }
      for (int m = 1; m < 64; m <<= 1) s += __shfl_xor(s, m, 64);
      if (ln == 0) sdot[c] = s;
    }
    __syncthreads();
    // wave-parallel selection (wave 0): lane-per-candidate + butterfly argmax
    if (wv == 0) {
      float bA = -INFINITY; int bI = 0x7fffffff;
      for (int c = ln; c < n; c += 64) {
        int k = sk[c];
        float rs = rel_sum[k];
        float act = act_of(xn, w_norm[k], sdot[c], rs, rs * (1.0f / 1024.0f));
        if (act > bA || (act == bA && k < bI)) { bA = act; bI = k; }
      }
#pragma unroll
      for (int m = 1; m < 64; m <<= 1) {
        float oa = __shfl_xor(bA, m, 64);
        int   oi = __shfl_xor(bI, m, 64);
        if (oa > bA || (oa == bA && oi < bI)) { bA = oa; bI = oi; }
      }
      if (ln == 0) {
        idx_int[b] = bI;
        out_idx[b] = (float)bI;
        atomicMax(&winner[bI], b);
        sBI = bI;
      }
    }
  } else {
    // safety valve (statistically unreachable)
    float bA = -INFINITY; int bI = 0x7fffffff;
    for (int k = wv; k < K_DIM; k += 4) {
      const float4* wr = (const float4*)(w + (size_t)k * D_DIM);
      float s = 0.f;
#pragma unroll
      for (int q = 0; q < 4; ++q) {
        float4 wv4 = wr[ln + 64 * q];
        s += xv[q].x * wv4.x + xv[q].y * wv4.y + xv[q].z * wv4.z + xv[q].w * wv4.w;
      }
      for (int m = 1; m < 64; m <<= 1) s += __shfl_xor(s, m, 64);
      if (ln == 0) {
        float rs = rel_sum[k];
        float act = act_of(xn, w_norm[k], s, rs, rs * (1.0f / 1024.0f));
        if (act > bA || (act == bA && k < bI)) { bA = act; bI = k; }
      }
    }
    if (ln == 0) { swA[wv] = bA; swI[wv] = bI; }
    __syncthreads();
    if (t == 0) {
      float bA2 = -INFINITY; int bI2 = 0x7fffffff;
#pragma unroll
      for (int c = 0; c < 4; ++c) {
        if (swA[c] > bA2 || (swA[c] == bA2 && swI[c] < bI2)) { bA2 = swA[c]; bI2 = swI[c]; }
      }
      idx_int[b] = bI2;
      out_idx[b] = (float)bI2;
      atomicMax(&winner[bI2], b);
      sBI = bI2;
    }
  }
  __syncthreads();

  const int bI = sBI;
  float4 xt = xr[t];
  float4 wt = ((const float4*)(w + (size_t)bI * D_DIM))[t];
  float s = (xt.x - wt.x) + (xt.y - wt.y) + (xt.z - wt.z) + (xt.w - wt.w);
  for (int m = 1; m < 64; m <<= 1) s += __shfl_xor(s, m, 64);
  if (ln == 0) sl[wv] = s;
  __syncthreads();
  if (t == 0) lparts[b] = sl[0] + sl[1] + sl[2] + sl[3];
}

// ---------------- scatter update / pass-through (+ fused loss reduction) ----------------
__global__ __launch_bounds__(256) void update_kernel(
    const float* __restrict__ x, const float* __restrict__ w,
    const float* __restrict__ ma, const float* __restrict__ rel,
    const int* __restrict__ winner, const float* __restrict__ lparts,
    float* __restrict__ out_w, float* __restrict__ out_ma,
    float* __restrict__ out_rel, float* __restrict__ out_loss) {
  const int k = blockIdx.x;
  const int t = threadIdx.x;

  if (k == K_DIM) {   // fused loss_final
    double acc = 0.0;
    for (int i = t; i < B_DIM; i += 256) acc += (double)lparts[i];
    for (int m = 1; m < 64; m <<= 1) acc += __shfl_xor(acc, m, 64);
    __shared__ double sa[4];
    if ((t & 63) == 0) sa[t >> 6] = acc;
    __syncthreads();
    if (t == 0)
      out_loss[0] = (float)(0.3 * (sa[0] + sa[1] + sa[2] + sa[3]) / (double)B_DIM);
    return;
  }

  const size_t ro = (size_t)k * D_DIM;
  const int bw = winner[k];
  if (bw < 0) {
    float4 a = ((const float4*)(w   + ro))[t];
    float4 b = ((const float4*)(ma  + ro))[t];
    float4 c = ((const float4*)(rel + ro))[t];
    ((float4*)(out_w   + ro))[t] = a;
    ((float4*)(out_ma  + ro))[t] = b;
    ((float4*)(out_rel + ro))[t] = c;
    return;
  }
  const float a_c = (float)(0.3 * 1e-4);
  const float omc = (float)(1.0 - 0.3 * 1e-4);
  float4 xv  = ((const float4*)(x  + (size_t)bw * D_DIM))[t];
  float4 wv4 = ((const float4*)(w  + ro))[t];
  float4 mav = ((const float4*)(ma + ro))[t];
  float4 nm;
  nm.x = a_c * fabsf(xv.x - wv4.x) + omc * mav.x;
  nm.y = a_c * fabsf(xv.y - wv4.y) + omc * mav.y;
  nm.z = a_c * fabsf(xv.z - wv4.z) + omc * mav.z;
  nm.w = a_c * fabsf(xv.w - wv4.w) + omc * mav.w;

  float tmx = fmaxf(fmaxf(nm.x, nm.y), fmaxf(nm.z, nm.w));
  float tmn = fminf(fminf(nm.x, nm.y), fminf(nm.z, nm.w));
  float tsm = nm.x + nm.y + nm.z + nm.w;
  for (int m = 1; m < 64; m <<= 1) {
    tmx = fmaxf(tmx, __shfl_xor(tmx, m, 64));
    tmn = fminf(tmn, __shfl_xor(tmn, m, 64));
    tsm += __shfl_xor(tsm, m, 64);
  }
  __shared__ float smx[4], smn[4], ssm[4];
  if ((t & 63) == 0) { smx[t >> 6] = tmx; smn[t >> 6] = tmn; ssm[t >> 6] = tsm; }
  __syncthreads();
  if (t == 0) {
    float m1 = fmaxf(fmaxf(smx[0], smx[1]), fmaxf(smx[2], smx[3]));
    float m2 = fminf(fminf(smn[0], smn[1]), fminf(smn[2], smn[3]));
    float s1 = ssm[0] + ssm[1] + ssm[2] + ssm[3];
    smx[0] = m1; smn[0] = m2; ssm[0] = s1;
  }
  __syncthreads();
  const float mx  = smx[0];
  const float mn  = smn[0];
  const float avg = ssm[0] * (1.0f / 1024.0f);
  const float den = 0.01f * (mx - mn);

  float4 rl;
  rl.x = 1.0f / (1.0f + expf((nm.x - avg) / den));
  rl.y = 1.0f / (1.0f + expf((nm.y - avg) / den));
  rl.z = 1.0f / (1.0f + expf((nm.z - avg) / den));
  rl.w = 1.0f / (1.0f + expf((nm.w - avg) / den));
  if (isnan(rl.x)) rl.x = 1.0f;
  if (isnan(rl.y)) rl.y = 1.0f;
  if (isnan(rl.z)) rl.z = 1.0f;
  if (isnan(rl.w)) rl.w = 1.0f;

  float4 nw;
  nw.x = wv4.x + 0.3f * (xv.x - wv4.x);
  nw.y = wv4.y + 0.3f * (xv.y - wv4.y);
  nw.z = wv4.z + 0.3f * (xv.z - wv4.z);
  nw.w = wv4.w + 0.3f * (xv.w - wv4.w);

  ((float4*)(out_w   + ro))[t] = nw;
  ((float4*)(out_ma  + ro))[t] = nm;
  ((float4*)(out_rel + ro))[t] = rl;
}

extern "C" void kernel_launch(void* const* d_in, const int* in_sizes, int n_in,
                              void* d_out, int out_size, void* d_ws, size_t ws_size,
                              hipStream_t stream) {
  const float* x   = (const float*)d_in[0];
  const float* w   = (const float*)d_in[1];
  const float* ma  = (const float*)d_in[2];
  const float* rel = (const float*)d_in[3];

  float* out      = (float*)d_out;
  float* out_loss = out;
  float* out_idx  = out + 1;
  float* out_w    = out + 1 + B_DIM;
  float* out_ma   = out_w  + (size_t)K_DIM * D_DIM;
  float* out_rel  = out_ma + (size_t)K_DIM * D_DIM;

  char* ws = (char*)d_ws;
  unsigned short* xh  = (unsigned short*)(ws + N_XH);
  unsigned short* whp = (unsigned short*)(ws + N_WH);
  float*  w_norm   = (float*)(ws + N_WN);
  float*  rel_sum  = (float*)(ws + N_RS);
  float*  x_norm   = (float*)(ws + N_XN);
  float*  rowmax_g = (float*)(ws + N_RMX);
  int*    cnt      = (int*)  (ws + N_CNT);
  int*    winner   = (int*)  (ws + N_WIN);
  float*  lparts   = (float*)(ws + N_LP);
  int*    idx_int  = (int*)  (ws + N_IDX);
  int*    cand_k   = (int*)  (ws + N_CK);
  float*  cand_a   = (float*)(ws + N_CA);

  prep_convert_kernel<<<(K_DIM + B_DIM) / 4, 256, 0, stream>>>(
      x, w, rel, xh, whp, w_norm, rel_sum, x_norm, rowmax_g, cnt, winner);
  mfma_screen_kernel<<<dim3(B_DIM / 128, K_DIM / 128), 256, 0, stream>>>(
      xh, whp, w_norm, rel_sum, x_norm, rowmax_g, cnt, cand_k, cand_a);
  scan_refine_kernel<<<B_DIM, 256, 0, stream>>>(
      cand_k, cand_a, cnt, rowmax_g, x, w, w_norm, rel_sum, x_norm,
      idx_int, out_idx, winner, lparts);
  update_kernel<<<K_DIM + 1, 256, 0, stream>>>(
      x, w, ma, rel, winner, lparts, out_w, out_ma, out_rel, out_loss);
}